// Round 6
// baseline (242.123 us; speedup 1.0000x reference)
//
#include <hip/hip_runtime.h>
#include <math.h>

#define BATCH 64
#define NN 512
#define DD 128
#define SLOPE 0.2f

typedef unsigned short u16;
typedef short bf16x8 __attribute__((ext_vector_type(8)));
typedef u16 u16x4 __attribute__((ext_vector_type(4)));
typedef u16 u16x8 __attribute__((ext_vector_type(8)));
typedef float f32x4 __attribute__((ext_vector_type(4)));

static __device__ __forceinline__ u16 f2bf(float x) {   // round-to-nearest-even
    unsigned int u = __float_as_uint(x);
    return (u16)((u + 0x7fffu + ((u >> 16) & 1u)) >> 16);
}
static __device__ __forceinline__ u16 bft(float x) {    // truncate
    return (u16)(__float_as_uint(x) >> 16);
}
static __device__ __forceinline__ float bf2f(u16 h) {
    return __uint_as_float(((unsigned int)h) << 16);
}

// ---------------------------------------------------------------------------
// k_prep (129 blocks x 256):
//   block 0: W^T split into bf16 hi(trunc)/lo(round)
//   blocks 1..128: colsum half-partials (thresh identity) + zero out
// ---------------------------------------------------------------------------
__global__ __launch_bounds__(256) void k_prep(const float* __restrict__ W,
                                              const float* __restrict__ E,
                                              u16* __restrict__ WtHi,
                                              u16* __restrict__ WtLo,
                                              float* __restrict__ cs2,
                                              float* __restrict__ out) {
    __shared__ float csr[8][128];
    int t = threadIdx.x;
    if (blockIdx.x == 0) {
        int n = t & 127, half = t >> 7;
        #pragma unroll
        for (int g = 0; g < 8; ++g) {
            u16x8 hv, lv;
            #pragma unroll
            for (int j = 0; j < 8; ++j) {
                float v = W[(size_t)(half * 64 + g * 8 + j) * DD + n];
                u16 h = bft(v);
                hv[j] = h;
                lv[j] = f2bf(v - bf2f(h));
            }
            *(u16x8*)&WtHi[(size_t)n * DD + half * 64 + g * 8] = hv;
            *(u16x8*)&WtLo[(size_t)n * DD + half * 64 + g * 8] = lv;
        }
    } else {
        int b = (blockIdx.x - 1) >> 1;
        int half = (blockIdx.x - 1) & 1;
        int c4 = t & 31, r0 = t >> 5;
        const float* Eb = E + ((size_t)b * NN + half * 256) * DD;
        float cp0 = 0.f, cp1 = 0.f, cp2 = 0.f, cp3 = 0.f;
        for (int k = 0; k < 32; ++k) {
            int row = r0 + k * 8;
            float4 v = *(const float4*)&Eb[(size_t)row * DD + c4 * 4];
            cp0 += v.x; cp1 += v.y; cp2 += v.z; cp3 += v.w;
        }
        csr[r0][c4 * 4 + 0] = cp0;
        csr[r0][c4 * 4 + 1] = cp1;
        csr[r0][c4 * 4 + 2] = cp2;
        csr[r0][c4 * 4 + 3] = cp3;
        if (t < 64) out[b * DD + half * 64 + t] = 0.f;   // zero out for atomics
        __syncthreads();
        if (t < 128) {
            float s = 0.f;
            #pragma unroll
            for (int g = 0; g < 8; ++g) s += csr[g][t];
            cs2[(size_t)half * BATCH * DD + b * DD + t] = s;
        }
    }
}

// ---------------------------------------------------------------------------
// k_z (256 blocks x 512): z = E@W split-bf16 MFMA. Block = (b, 128 rows).
// 8 waves = 4 strip-groups(2x16 rows) x 2 col-halves(4 nt). W frags persist
// in registers. Emits Ebf (bf16-trunc+... hi of E? -> rounded hi for scores),
// zT [B][D][N] bf16, el/er fp32.
// ---------------------------------------------------------------------------
__global__ __launch_bounds__(512, 2) void k_z(const float* __restrict__ E,
                                              const u16* __restrict__ WtHi,
                                              const u16* __restrict__ WtLo,
                                              const float* __restrict__ al,
                                              const float* __restrict__ ar,
                                              u16* __restrict__ Ebf,
                                              u16* __restrict__ zT,
                                              float* __restrict__ el,
                                              float* __restrict__ er) {
    int bid = blockIdx.x;
    int b = (bid & 7) * 8 + (bid >> 5);       // XCD swizzle
    int rg = (bid >> 3) & 3;                  // 128-row group
    int t = threadIdx.x;
    int w = t >> 6;
    int lane = t & 63;
    int l15 = lane & 15;
    int quad = lane >> 4;
    int sg = w >> 1;                          // strip-group 0..3
    int ch = w & 1;                           // col-half (nt base = ch*4)

    __shared__ float elp_s[128], erp_s[128];
    for (int i = t; i < 128; i += 512) { elp_s[i] = 0.f; erp_s[i] = 0.f; }
    __syncthreads();

    // persistent W^T frags for 4 nt
    bf16x8 bh[4][4], bl[4][4];
    float a_l[4], a_r[4];
    #pragma unroll
    for (int c = 0; c < 4; ++c) {
        int nt = ch * 4 + c;
        #pragma unroll
        for (int ks = 0; ks < 4; ++ks) {
            bh[c][ks] = *(const bf16x8*)(WtHi + (size_t)(nt * 16 + l15) * DD + ks * 32 + quad * 8);
            bl[c][ks] = *(const bf16x8*)(WtLo + (size_t)(nt * 16 + l15) * DD + ks * 32 + quad * 8);
        }
        a_l[c] = al[nt * 16 + l15];
        a_r[c] = ar[nt * 16 + l15];
    }

    #pragma unroll
    for (int si = 0; si < 2; ++si) {
        int s = sg * 2 + si;                  // strip 0..7
        int row = rg * 128 + s * 16 + l15;
        const float* Er = E + ((size_t)b * NN + row) * DD;

        bf16x8 ah[4], alo[4];
        #pragma unroll
        for (int ks = 0; ks < 4; ++ks) {
            float4 v0 = *(const float4*)(Er + ks * 32 + quad * 8);
            float4 v1 = *(const float4*)(Er + ks * 32 + quad * 8 + 4);
            float vv[8] = {v0.x, v0.y, v0.z, v0.w, v1.x, v1.y, v1.z, v1.w};
            u16x8 hv, lv;
            #pragma unroll
            for (int j = 0; j < 8; ++j) {
                u16 h = f2bf(vv[j]);          // rounded hi (used for scores too)
                hv[j] = h;
                lv[j] = f2bf(vv[j] - bf2f(h));
            }
            ah[ks] = (bf16x8)hv;
            alo[ks] = (bf16x8)lv;
            if (ch == 0)
                *(u16x8*)&Ebf[((size_t)b * NN + row) * DD + ks * 32 + quad * 8] = hv;
        }

        f32x4 C[4];
        #pragma unroll
        for (int c = 0; c < 4; ++c) C[c] = (f32x4){0.f, 0.f, 0.f, 0.f};
        #pragma unroll
        for (int ks = 0; ks < 4; ++ks)
            #pragma unroll
            for (int c = 0; c < 4; ++c) {
                C[c] = __builtin_amdgcn_mfma_f32_16x16x32_bf16(ah[ks],  bh[c][ks], C[c], 0, 0, 0);
                C[c] = __builtin_amdgcn_mfma_f32_16x16x32_bf16(alo[ks], bh[c][ks], C[c], 0, 0, 0);
                C[c] = __builtin_amdgcn_mfma_f32_16x16x32_bf16(ah[ks],  bl[c][ks], C[c], 0, 0, 0);
            }

        // zT stores + el/er partials
        float elp[4] = {0.f, 0.f, 0.f, 0.f};
        float erp[4] = {0.f, 0.f, 0.f, 0.f};
        #pragma unroll
        for (int c = 0; c < 4; ++c) {
            u16x4 zp;
            #pragma unroll
            for (int r = 0; r < 4; ++r) {
                zp[r] = f2bf(C[c][r]);
                elp[r] += C[c][r] * a_l[c];
                erp[r] += C[c][r] * a_r[c];
            }
            *(u16x4*)&zT[((size_t)b * DD + (ch * 4 + c) * 16 + l15) * NN
                         + rg * 128 + s * 16 + quad * 4] = zp;
        }
        #pragma unroll
        for (int r = 0; r < 4; ++r) {
            float vl = elp[r], vr = erp[r];
            #pragma unroll
            for (int off = 8; off > 0; off >>= 1) {
                vl += __shfl_down(vl, off);
                vr += __shfl_down(vr, off);
            }
            if (l15 == 0) {
                atomicAdd(&elp_s[s * 16 + quad * 4 + r], vl);
                atomicAdd(&erp_s[s * 16 + quad * 4 + r], vr);
            }
        }
    }
    __syncthreads();
    if (t < 128) {
        el[b * NN + rg * 128 + t] = elp_s[t];
        er[b * NN + rg * 128 + t] = erp_s[t];
    }
}

// ---------------------------------------------------------------------------
// k_main (1024 blocks x 512): fused masked-GAT attention, wave-private,
// ZERO in-loop barriers. Block = (b, 32 j). 8 waves = 2 j-tiles x 4 i-quarters.
// Z via ones-B MFMA. Cross-wave H/Z reduce once via LDS atomics.
// ---------------------------------------------------------------------------
__global__ __launch_bounds__(512, 2) void k_main(const u16* __restrict__ Ebf,
                                                 const u16* __restrict__ zT,
                                                 const float* __restrict__ el,
                                                 const float* __restrict__ er,
                                                 const float* __restrict__ cs2,
                                                 const float* __restrict__ bias,
                                                 float* __restrict__ out) {
    int bid = blockIdx.x;
    int b = (bid & 7) * 8 + (bid >> 7);       // XCD swizzle (16 blocks/batch)
    int j0 = ((bid >> 3) & 15) * 32;
    int t = threadIdx.x;
    int w = t >> 6;
    int lane = t & 63;
    int l15 = lane & 15;
    int quad = lane >> 4;
    int jt = w & 1;                           // j-tile (16 j)
    int ih = w >> 1;                          // i-quarter (128 i)
    int jb = j0 + jt * 16;

    const u16* Eb = Ebf + (size_t)b * NN * DD;
    const u16* zTb = zT + (size_t)b * DD * NN;

    __shared__ u16 pT[8][16][56];             // wave-private P^T, 112B stride
    __shared__ float hsum[32][129];
    __shared__ float zsum[32];
    __shared__ float osum[128];
    __shared__ float tred[2];

    for (int i = t; i < 32 * 129; i += 512) (&hsum[0][0])[i] = 0.f;
    if (t < 32) zsum[t] = 0.f;
    if (t < 128) {
        osum[t] = 0.f;
        float c = cs2[b * DD + t] + cs2[BATCH * DD + b * DD + t];
        float v = c * c;
        #pragma unroll
        for (int off = 32; off > 0; off >>= 1) v += __shfl_down(v, off);
        if ((t & 63) == 0) tred[t >> 6] = v;
    }

    // persistent Ej B-frags (16 j)
    bf16x8 bEj[4];
    #pragma unroll
    for (int ks = 0; ks < 4; ++ks)
        bEj[ks] = *(const bf16x8*)(Eb + (size_t)(jb + l15) * DD + ks * 32 + quad * 8);
    float er_v = er[b * NN + jb + l15];

    f32x4 H[8];
    #pragma unroll
    for (int nt = 0; nt < 8; ++nt) H[nt] = (f32x4){0.f, 0.f, 0.f, 0.f};
    f32x4 CZ = (f32x4){0.f, 0.f, 0.f, 0.f};
    bf16x8 one8;
    #pragma unroll
    for (int j = 0; j < 8; ++j) one8[j] = (short)0x3F80;

    __syncthreads();                          // init visible; no loop barriers
    float thr = (tred[0] + tred[1]) * (1.0f / ((float)NN * (float)NN));

    #pragma unroll 2
    for (int p = 0; p < 4; ++p) {
        int ip0 = ih * 128 + p * 32;

        // aggregation B-frags for this 32-i pair (issued early)
        bf16x8 bz[8];
        #pragma unroll
        for (int nt = 0; nt < 8; ++nt)
            bz[nt] = *(const bf16x8*)(zTb + (size_t)(nt * 16 + l15) * NN + ip0 + quad * 8);

        #pragma unroll
        for (int s = 0; s < 2; ++s) {
            int i0 = ip0 + s * 16;
            bf16x8 aE[4];
            #pragma unroll
            for (int ks = 0; ks < 4; ++ks)
                aE[ks] = *(const bf16x8*)(Eb + (size_t)(i0 + l15) * DD + ks * 32 + quad * 8);

            f32x4 S = (f32x4){0.f, 0.f, 0.f, 0.f};
            #pragma unroll
            for (int ks = 0; ks < 4; ++ks)
                S = __builtin_amdgcn_mfma_f32_16x16x32_bf16(aE[ks], bEj[ks], S, 0, 0, 0);

            float4 el4 = *(const float4*)(el + b * NN + i0 + quad * 4);
            float elv[4] = {el4.x, el4.y, el4.z, el4.w};
            u16x4 pk;
            if (i0 == jb) {                   // diagonal sub-tile: self-loops
                #pragma unroll
                for (int r = 0; r < 4; ++r) {
                    float x = elv[r] + er_v;
                    float lg = x > 0.f ? x : SLOPE * x;
                    bool keep = (S[r] > thr) || ((i0 + quad * 4 + r) == (jb + l15));
                    pk[r] = f2bf(keep ? __expf(lg) : 0.f);
                }
            } else {
                #pragma unroll
                for (int r = 0; r < 4; ++r) {
                    float x = elv[r] + er_v;
                    float lg = x > 0.f ? x : SLOPE * x;
                    pk[r] = f2bf((S[r] > thr) ? __expf(lg) : 0.f);
                }
            }
            *(u16x4*)&pT[w][l15][s * 16 + quad * 4] = pk;   // [j][i-local]
        }

        // wave-private C->A transform (program-order DS, lgkmcnt only)
        bf16x8 ap = *(const bf16x8*)&pT[w][l15][quad * 8];

        CZ = __builtin_amdgcn_mfma_f32_16x16x32_bf16(ap, one8, CZ, 0, 0, 0);
        #pragma unroll
        for (int nt = 0; nt < 8; ++nt)
            H[nt] = __builtin_amdgcn_mfma_f32_16x16x32_bf16(ap, bz[nt], H[nt], 0, 0, 0);
    }

    // ---- cross-wave reduce (once)
    if (l15 == 0) {
        #pragma unroll
        for (int r = 0; r < 4; ++r)
            atomicAdd(&zsum[jt * 16 + quad * 4 + r], CZ[r]);
    }
    #pragma unroll
    for (int nt = 0; nt < 8; ++nt)
        #pragma unroll
        for (int r = 0; r < 4; ++r)
            atomicAdd(&hsum[jt * 16 + quad * 4 + r][nt * 16 + l15], H[nt][r]);
    __syncthreads();
    if (t < 32) zsum[t] = 1.0f / zsum[t];     // self-loop guarantees > 0
    __syncthreads();

    // ---- epilogue: /Z, +bias, elu, partial mean over 32 j, atomic out
    int d = t & 127, g = t >> 7;              // g: 8 j's each
    float bsv = bias[d];
    float acc = 0.f;
    #pragma unroll
    for (int jj = 0; jj < 8; ++jj) {
        int j = g * 8 + jj;
        float v = hsum[j][d] * zsum[j] + bsv;
        v = v > 0.f ? v : (__expf(v) - 1.f);
        acc += v;
    }
    atomicAdd(&osum[d], acc);
    __syncthreads();
    if (t < 128) atomicAdd(&out[b * DD + t], osum[t] * (1.0f / NN));
}

// ---------------------------------------------------------------------------
extern "C" void kernel_launch(void* const* d_in, const int* in_sizes, int n_in,
                              void* d_out, int out_size, void* d_ws, size_t ws_size,
                              hipStream_t stream) {
    const float* E    = (const float*)d_in[0];
    const float* W    = (const float*)d_in[1];
    const float* al   = (const float*)d_in[2];
    const float* ar   = (const float*)d_in[3];
    const float* bias = (const float*)d_in[4];
    float* out = (float*)d_out;

    u16* Ebf = (u16*)d_ws;                                     // 8 MB
    u16* zTb = Ebf + (size_t)BATCH * NN * DD;                  // 8 MB
    u16* WtHi = zTb + (size_t)BATCH * NN * DD;                 // 32 KB
    u16* WtLo = WtHi + (size_t)DD * DD;                        // 32 KB
    float* el  = (float*)(WtLo + (size_t)DD * DD);             // 128 KB
    float* er  = el + (size_t)BATCH * NN;                      // 128 KB
    float* cs2 = er + (size_t)BATCH * NN;                      // 64 KB (2 halves)

    k_prep<<<dim3(129), dim3(256), 0, stream>>>(W, E, WtHi, WtLo, cs2, out);
    k_z<<<dim3(256), dim3(512), 0, stream>>>(E, WtHi, WtLo, al, ar, Ebf, zTb, el, er);
    k_main<<<dim3(1024), dim3(512), 0, stream>>>(Ebf, zTb, el, er, cs2, bias, out);
}

// Round 7
// 125.459 us; speedup vs baseline: 1.9299x; 1.9299x over previous
//
#include <hip/hip_runtime.h>
#include <math.h>

#define BATCH 64
#define NN 512
#define DD 128
#define SLOPE 0.2f

typedef unsigned short u16;
typedef short bf16x8 __attribute__((ext_vector_type(8)));
typedef u16 u16x4 __attribute__((ext_vector_type(4)));
typedef u16 u16x8 __attribute__((ext_vector_type(8)));
typedef float f32x4 __attribute__((ext_vector_type(4)));

static __device__ __forceinline__ u16 f2bf(float x) {   // round-to-nearest-even
    unsigned int u = __float_as_uint(x);
    return (u16)((u + 0x7fffu + ((u >> 16) & 1u)) >> 16);
}
static __device__ __forceinline__ float bf2f(u16 h) {
    return __uint_as_float(((unsigned int)h) << 16);
}
// async global->LDS DMA, 16B per lane. lds ptr MUST be wave-uniform;
// HW writes lds + lane*16.
static __device__ __forceinline__ void gld16(const u16* g, u16* lds) {
    __builtin_amdgcn_global_load_lds(
        (const __attribute__((address_space(1))) unsigned int*)g,
        (__attribute__((address_space(3))) unsigned int*)lds, 16, 0, 0);
}

// ---------------------------------------------------------------------------
// k_prep (129 blocks x 256): block 0: W^T bf16 hi/lo split;
// blocks 1..128: colsum half-partials + zero `out`.
// ---------------------------------------------------------------------------
__global__ __launch_bounds__(256) void k_prep(const float* __restrict__ W,
                                              const float* __restrict__ E,
                                              u16* __restrict__ WtHi,
                                              u16* __restrict__ WtLo,
                                              float* __restrict__ cs2,
                                              float* __restrict__ out) {
    __shared__ float csr[8][128];
    int t = threadIdx.x;
    if (blockIdx.x == 0) {
        int n = t & 127, half = t >> 7;
        #pragma unroll
        for (int g = 0; g < 8; ++g) {
            u16x8 hv, lv;
            #pragma unroll
            for (int j = 0; j < 8; ++j) {
                float v = W[(size_t)(half * 64 + g * 8 + j) * DD + n];
                u16 h = f2bf(v);
                hv[j] = h;
                lv[j] = f2bf(v - bf2f(h));
            }
            *(u16x8*)&WtHi[(size_t)n * DD + half * 64 + g * 8] = hv;
            *(u16x8*)&WtLo[(size_t)n * DD + half * 64 + g * 8] = lv;
        }
    } else {
        int b = (blockIdx.x - 1) >> 1;
        int half = (blockIdx.x - 1) & 1;
        int c4 = t & 31, r0 = t >> 5;
        const float* Eb = E + ((size_t)b * NN + half * 256) * DD;
        float cp0 = 0.f, cp1 = 0.f, cp2 = 0.f, cp3 = 0.f;
        for (int k = 0; k < 32; ++k) {
            int row = r0 + k * 8;
            float4 v = *(const float4*)&Eb[(size_t)row * DD + c4 * 4];
            cp0 += v.x; cp1 += v.y; cp2 += v.z; cp3 += v.w;
        }
        csr[r0][c4 * 4 + 0] = cp0;
        csr[r0][c4 * 4 + 1] = cp1;
        csr[r0][c4 * 4 + 2] = cp2;
        csr[r0][c4 * 4 + 3] = cp3;
        if (t < 64) out[b * DD + half * 64 + t] = 0.f;
        __syncthreads();
        if (t < 128) {
            float s = 0.f;
            #pragma unroll
            for (int g = 0; g < 8; ++g) s += csr[g][t];
            cs2[(size_t)half * BATCH * DD + b * DD + t] = s;
        }
    }
}

// ---------------------------------------------------------------------------
// k_z (256 blocks x 512): split-bf16 MFMA z = E@W. Emits Ebf, zT, el, er.
// ---------------------------------------------------------------------------
__global__ __launch_bounds__(512) void k_z(const float* __restrict__ E,
                                           const u16* __restrict__ WtHi,
                                           const u16* __restrict__ WtLo,
                                           const float* __restrict__ al,
                                           const float* __restrict__ ar,
                                           u16* __restrict__ Ebf,
                                           u16* __restrict__ zT,
                                           float* __restrict__ el,
                                           float* __restrict__ er) {
    int bid = blockIdx.x;
    int b = (bid & 7) * 8 + (bid >> 5);       // XCD swizzle
    int rg = (bid >> 3) & 3;                  // 128-row group
    int t = threadIdx.x;
    int w = t >> 6;
    int lane = t & 63;
    int l15 = lane & 15;
    int quad = lane >> 4;
    int sg = w >> 1;
    int ch = w & 1;

    __shared__ float elp_s[128], erp_s[128];
    for (int i = t; i < 128; i += 512) { elp_s[i] = 0.f; erp_s[i] = 0.f; }
    __syncthreads();

    bf16x8 bh[4][4], bl[4][4];
    float a_l[4], a_r[4];
    #pragma unroll
    for (int c = 0; c < 4; ++c) {
        int nt = ch * 4 + c;
        #pragma unroll
        for (int ks = 0; ks < 4; ++ks) {
            bh[c][ks] = *(const bf16x8*)(WtHi + (size_t)(nt * 16 + l15) * DD + ks * 32 + quad * 8);
            bl[c][ks] = *(const bf16x8*)(WtLo + (size_t)(nt * 16 + l15) * DD + ks * 32 + quad * 8);
        }
        a_l[c] = al[nt * 16 + l15];
        a_r[c] = ar[nt * 16 + l15];
    }

    #pragma unroll
    for (int si = 0; si < 2; ++si) {
        int s = sg * 2 + si;
        int row = rg * 128 + s * 16 + l15;
        const float* Er = E + ((size_t)b * NN + row) * DD;

        bf16x8 ah[4], alo[4];
        #pragma unroll
        for (int ks = 0; ks < 4; ++ks) {
            float4 v0 = *(const float4*)(Er + ks * 32 + quad * 8);
            float4 v1 = *(const float4*)(Er + ks * 32 + quad * 8 + 4);
            float vv[8] = {v0.x, v0.y, v0.z, v0.w, v1.x, v1.y, v1.z, v1.w};
            u16x8 hv, lv;
            #pragma unroll
            for (int j = 0; j < 8; ++j) {
                u16 h = f2bf(vv[j]);
                hv[j] = h;
                lv[j] = f2bf(vv[j] - bf2f(h));
            }
            ah[ks] = (bf16x8)hv;
            alo[ks] = (bf16x8)lv;
            if (ch == 0)
                *(u16x8*)&Ebf[((size_t)b * NN + row) * DD + ks * 32 + quad * 8] = hv;
        }

        f32x4 C[4];
        #pragma unroll
        for (int c = 0; c < 4; ++c) C[c] = (f32x4){0.f, 0.f, 0.f, 0.f};
        #pragma unroll
        for (int ks = 0; ks < 4; ++ks)
            #pragma unroll
            for (int c = 0; c < 4; ++c) {
                C[c] = __builtin_amdgcn_mfma_f32_16x16x32_bf16(ah[ks],  bh[c][ks], C[c], 0, 0, 0);
                C[c] = __builtin_amdgcn_mfma_f32_16x16x32_bf16(alo[ks], bh[c][ks], C[c], 0, 0, 0);
                C[c] = __builtin_amdgcn_mfma_f32_16x16x32_bf16(ah[ks],  bl[c][ks], C[c], 0, 0, 0);
            }

        float elp[4] = {0.f, 0.f, 0.f, 0.f};
        float erp[4] = {0.f, 0.f, 0.f, 0.f};
        #pragma unroll
        for (int c = 0; c < 4; ++c) {
            u16x4 zp;
            #pragma unroll
            for (int r = 0; r < 4; ++r) {
                zp[r] = f2bf(C[c][r]);
                elp[r] += C[c][r] * a_l[c];
                erp[r] += C[c][r] * a_r[c];
            }
            *(u16x4*)&zT[((size_t)b * DD + (ch * 4 + c) * 16 + l15) * NN
                         + rg * 128 + s * 16 + quad * 4] = zp;
        }
        #pragma unroll
        for (int r = 0; r < 4; ++r) {
            float vl = elp[r], vr = erp[r];
            #pragma unroll
            for (int off = 8; off > 0; off >>= 1) {
                vl += __shfl_down(vl, off);
                vr += __shfl_down(vr, off);
            }
            if (l15 == 0) {
                atomicAdd(&elp_s[s * 16 + quad * 4 + r], vl);
                atomicAdd(&erp_s[s * 16 + quad * 4 + r], vr);
            }
        }
    }
    __syncthreads();
    if (t < 128) {
        el[b * NN + rg * 128 + t] = elp_s[t];
        er[b * NN + rg * 128 + t] = erp_s[t];
    }
}

// ---------------------------------------------------------------------------
// k_main (512 blocks x 256): m97-style fused attention. Block = (b, 64 j).
// Per 64-i chunk: global_load_lds stage Ei(16KB)+zT(16KB); scores (LDS A x
// reg B); exp -> wave-private pT; agg MFMA (LDS B). 2 barriers/chunk.
// Wave w owns j rows [j0+16w, j0+16w+16) -- no cross-wave H reduction.
// ---------------------------------------------------------------------------
__global__ __launch_bounds__(256, 3) void k_main(const u16* __restrict__ Ebf,
                                                 const u16* __restrict__ zT,
                                                 const float* __restrict__ el,
                                                 const float* __restrict__ er,
                                                 const float* __restrict__ cs2,
                                                 const float* __restrict__ bias,
                                                 float* __restrict__ out) {
    int bid = blockIdx.x;
    int b = (bid & 7) * 8 + (bid >> 6);       // XCD swizzle (8 blocks/batch)
    int j0 = ((bid >> 3) & 7) * 64;
    int t = threadIdx.x;
    int w = t >> 6;
    int lane = t & 63;
    int l15 = lane & 15;
    int quad = lane >> 4;
    int jb = j0 + w * 16;

    const u16* Eb = Ebf + (size_t)b * NN * DD;
    const u16* zTb = zT + (size_t)b * DD * NN;

    __shared__ u16 Ei[64 * DD];       // 64 i-rows x 256B, row-major (no pad)
    __shared__ u16 zTile[DD * 64];    // 128 d-rows x 128B
    __shared__ u16 pT[4][16][72];     // wave-private P^T (j x i), +8 pad
    __shared__ float tred[2];

    // thresh = ||colsum||^2 / N^2
    if (t < 128) {
        float c = cs2[b * DD + t] + cs2[BATCH * DD + b * DD + t];
        float v = c * c;
        #pragma unroll
        for (int off = 32; off > 0; off >>= 1) v += __shfl_down(v, off);
        if ((t & 63) == 0) tred[t >> 6] = v;
    }

    // persistent Ej B-frags (this wave's 16 j)
    bf16x8 bEj[4];
    #pragma unroll
    for (int ks = 0; ks < 4; ++ks)
        bEj[ks] = *(const bf16x8*)(Eb + (size_t)(jb + l15) * DD + ks * 32 + quad * 8);
    float er_v = er[b * NN + jb + l15];

    f32x4 H[8];
    #pragma unroll
    for (int nt = 0; nt < 8; ++nt) H[nt] = (f32x4){0.f, 0.f, 0.f, 0.f};
    f32x4 CZ = (f32x4){0.f, 0.f, 0.f, 0.f};
    bf16x8 one8;
    #pragma unroll
    for (int j = 0; j < 8; ++j) one8[j] = (short)0x3F80;

    __syncthreads();
    float thr = (tred[0] + tred[1]) * (1.0f / ((float)NN * (float)NN));

    for (int c = 0; c < 8; ++c) {
        int i0 = c * 64;

        // ---- async stage: Ei rows (wave w: rows 16w..16w+15) and
        //      zTile d-rows (wave w: 32w..32w+31). 1KB per instruction.
        #pragma unroll
        for (int g = 0; g < 4; ++g) {
            const u16* gp = Eb + (size_t)(i0 + w * 16 + g * 4 + (lane >> 4)) * DD + (lane & 15) * 8;
            gld16(gp, &Ei[(w * 16 + g * 4) * DD]);
        }
        #pragma unroll
        for (int g = 0; g < 4; ++g) {
            const u16* gp = zTb + (size_t)(w * 32 + g * 8 + (lane >> 3)) * NN + i0 + (lane & 7) * 8;
            gld16(gp, &zTile[(w * 32 + g * 8) * 64]);
        }
        __syncthreads();   // drains DMA (vmcnt) + all waves staged

        // ---- scores S[i][j] for 4 i-subtiles; C: lane=j_local, regs=i
        #pragma unroll
        for (int it = 0; it < 4; ++it) {
            bf16x8 aE[4];
            #pragma unroll
            for (int ks = 0; ks < 4; ++ks)
                aE[ks] = *(const bf16x8*)&Ei[(it * 16 + l15) * DD + ks * 32 + quad * 8];
            f32x4 S = (f32x4){0.f, 0.f, 0.f, 0.f};
            #pragma unroll
            for (int ks = 0; ks < 4; ++ks)
                S = __builtin_amdgcn_mfma_f32_16x16x32_bf16(aE[ks], bEj[ks], S, 0, 0, 0);

            float4 el4 = *(const float4*)(el + b * NN + i0 + it * 16 + quad * 4);
            float elv[4] = {el4.x, el4.y, el4.z, el4.w};
            u16x4 pk;
            if (i0 + it * 16 == jb) {          // diagonal subtile: self-loops
                #pragma unroll
                for (int r = 0; r < 4; ++r) {
                    float x = elv[r] + er_v;
                    float lg = x > 0.f ? x : SLOPE * x;
                    bool keep = (S[r] > thr) || ((quad * 4 + r) == l15);
                    pk[r] = f2bf(keep ? __expf(lg) : 0.f);
                }
            } else {
                #pragma unroll
                for (int r = 0; r < 4; ++r) {
                    float x = elv[r] + er_v;
                    float lg = x > 0.f ? x : SLOPE * x;
                    pk[r] = f2bf((S[r] > thr) ? __expf(lg) : 0.f);
                }
            }
            *(u16x4*)&pT[w][l15][it * 16 + quad * 4] = pk;
        }

        // ---- wave-private C->A transform (lgkmcnt only, no barrier)
        bf16x8 ap[2];
        #pragma unroll
        for (int ks = 0; ks < 2; ++ks)
            ap[ks] = *(const bf16x8*)&pT[w][l15][ks * 32 + quad * 8];

        // ---- aggregation: H[j][d] += P.z ; Z via ones-B
        #pragma unroll
        for (int ks = 0; ks < 2; ++ks) {
            CZ = __builtin_amdgcn_mfma_f32_16x16x32_bf16(ap[ks], one8, CZ, 0, 0, 0);
            #pragma unroll
            for (int nt = 0; nt < 8; ++nt) {
                bf16x8 bz = *(const bf16x8*)&zTile[(nt * 16 + l15) * 64 + ks * 32 + quad * 8];
                H[nt] = __builtin_amdgcn_mfma_f32_16x16x32_bf16(ap[ks], bz, H[nt], 0, 0, 0);
            }
        }
        __syncthreads();   // all waves done reading before next stage
    }

    // ---- epilogue: /Z, +bias, elu, sum over this wave's 16 j, atomic out
    float zinv[4];
    #pragma unroll
    for (int r = 0; r < 4; ++r) zinv[r] = 1.0f / CZ[r];   // self-loop > 0

    #pragma unroll
    for (int nt = 0; nt < 8; ++nt) {
        float bsv = bias[nt * 16 + l15];
        float acc = 0.f;
        #pragma unroll
        for (int r = 0; r < 4; ++r) {
            float v = H[nt][r] * zinv[r] + bsv;
            v = v > 0.f ? v : (__expf(v) - 1.f);
            acc += v;
        }
        acc += __shfl_down(acc, 32);
        acc += __shfl_down(acc, 16);
        if (lane < 16) atomicAdd(&out[b * DD + nt * 16 + lane], acc * (1.0f / NN));
    }
}

// ---------------------------------------------------------------------------
extern "C" void kernel_launch(void* const* d_in, const int* in_sizes, int n_in,
                              void* d_out, int out_size, void* d_ws, size_t ws_size,
                              hipStream_t stream) {
    const float* E    = (const float*)d_in[0];
    const float* W    = (const float*)d_in[1];
    const float* al   = (const float*)d_in[2];
    const float* ar   = (const float*)d_in[3];
    const float* bias = (const float*)d_in[4];
    float* out = (float*)d_out;

    u16* Ebf = (u16*)d_ws;                                     // 8 MB
    u16* zTb = Ebf + (size_t)BATCH * NN * DD;                  // 8 MB
    u16* WtHi = zTb + (size_t)BATCH * NN * DD;                 // 32 KB
    u16* WtLo = WtHi + (size_t)DD * DD;                        // 32 KB
    float* el  = (float*)(WtLo + (size_t)DD * DD);             // 128 KB
    float* er  = el + (size_t)BATCH * NN;                      // 128 KB
    float* cs2 = er + (size_t)BATCH * NN;                      // 64 KB

    k_prep<<<dim3(129), dim3(256), 0, stream>>>(W, E, WtHi, WtLo, cs2, out);
    k_z<<<dim3(256), dim3(512), 0, stream>>>(E, WtHi, WtLo, al, ar, Ebf, zTb, el, er);
    k_main<<<dim3(512), dim3(256), 0, stream>>>(Ebf, zTb, el, er, cs2, bias, out);
}